// Round 6
// baseline (223.369 us; speedup 1.0000x reference)
//
#include <hip/hip_runtime.h>
#include <hip/hip_bf16.h>

#define N_ROWS 8192
#define DIM 512
#define SCALE 2.659f
#define MAXLOGIT 2.659f
#define LOG2E 1.4426950408889634f
#define NCHUNK 16
#define CHUNK 512
#define BM 128
#define BN 128
#define NCLS 128

typedef __attribute__((ext_vector_type(8))) short short8;
typedef __attribute__((ext_vector_type(4))) float f32x4;

// zero region: rs(8192) + cs(8192) + c_txt(65536) + c_img(65536) + cnt(128)
// = 147584 f32 = 36896 float4
#define ZERO_F4 36896

__device__ __forceinline__ unsigned short f2bf(float f) {
    unsigned int u = __float_as_uint(f);
    u += 0x7fffu + ((u >> 16) & 1u);
    return (unsigned short)(u >> 16);
}

// ---------------------------------------------------------------- normalize
// One wave handles image row i AND text row i: computes both norms, writes
// both bf16 rows, and emits the self-dot <a_i,b_i> (needed when label==-1).
// Also zero-initializes rs/cs/c_txt/c_img/cnt accumulators and out[0].
__global__ __launch_bounds__(256) void norm_cast_kernel(
    const float* __restrict__ text, const float* __restrict__ image,
    const int* __restrict__ labels,
    unsigned short* __restrict__ imgn, unsigned short* __restrict__ txtn,
    float4* __restrict__ zbase, float* __restrict__ sd, float* __restrict__ out)
{
    int zi = blockIdx.x * 256 + threadIdx.x;
    if (zi < ZERO_F4) zbase[zi] = make_float4(0.f, 0.f, 0.f, 0.f);
    if (zi == 0) out[0] = 0.f;

    int row  = blockIdx.x * 4 + (threadIdx.x >> 6);
    int lane = threadIdx.x & 63;
    const float4* si = (const float4*)(image + (size_t)row * DIM) + lane * 2;
    const float4* st = (const float4*)(text  + (size_t)row * DIM) + lane * 2;
    float4 a = si[0], b = si[1], c = st[0], d = st[1];
    float ssa = a.x*a.x + a.y*a.y + a.z*a.z + a.w*a.w
              + b.x*b.x + b.y*b.y + b.z*b.z + b.w*b.w;
    float sst = c.x*c.x + c.y*c.y + c.z*c.z + c.w*c.w
              + d.x*d.x + d.y*d.y + d.z*d.z + d.w*d.w;
    float sab = a.x*c.x + a.y*c.y + a.z*c.z + a.w*c.w
              + b.x*d.x + b.y*d.y + b.z*d.z + b.w*d.w;
    #pragma unroll
    for (int m = 1; m < 64; m <<= 1) {
        ssa += __shfl_xor(ssa, m, 64);
        sst += __shfl_xor(sst, m, 64);
        sab += __shfl_xor(sab, m, 64);
    }
    float sca = 1.0f / fmaxf(sqrtf(ssa), 1e-12f);
    float sct = 1.0f / fmaxf(sqrtf(sst), 1e-12f);
    uint4 oi, ot;
    oi.x = (unsigned)f2bf(a.x*sca) | ((unsigned)f2bf(a.y*sca) << 16);
    oi.y = (unsigned)f2bf(a.z*sca) | ((unsigned)f2bf(a.w*sca) << 16);
    oi.z = (unsigned)f2bf(b.x*sca) | ((unsigned)f2bf(b.y*sca) << 16);
    oi.w = (unsigned)f2bf(b.z*sca) | ((unsigned)f2bf(b.w*sca) << 16);
    ot.x = (unsigned)f2bf(c.x*sct) | ((unsigned)f2bf(c.y*sct) << 16);
    ot.y = (unsigned)f2bf(c.z*sct) | ((unsigned)f2bf(c.w*sct) << 16);
    ot.z = (unsigned)f2bf(d.x*sct) | ((unsigned)f2bf(d.y*sct) << 16);
    ot.w = (unsigned)f2bf(d.z*sct) | ((unsigned)f2bf(d.w*sct) << 16);
    *((uint4*)(imgn + (size_t)row * DIM) + lane) = oi;
    *((uint4*)(txtn + (size_t)row * DIM) + lane) = ot;
    if (lane == 0)
        sd[row] = (labels[row] < 0) ? sab * sca * sct : 0.0f;
}

// ---------------------------------------------------------------- class sums
// 2048 blocks = (8 label-slices) x (128 classes) x (2 matrices). Each block
// scans 1K labels, gathers its ~10 matching rows, atomically accumulates
// into c_txt/c_img (f32, zeroed by norm_cast) and cnt.
__global__ __launch_bounds__(256) void class_sum_kernel(
    const unsigned short* __restrict__ imgn, const unsigned short* __restrict__ txtn,
    const int* __restrict__ labels,
    float* __restrict__ c_txt, float* __restrict__ c_img, int* __restrict__ cnt)
{
    __shared__ int list[1024];
    __shared__ int lcount;
    int blk = blockIdx.x;
    int cls = blk & (NCLS - 1);
    int mat = (blk >> 7) & 1;                  // 0: txt sums, 1: img sums
    int slc = blk >> 8;                        // 0..7
    const unsigned* src = (const unsigned*)(mat ? imgn : txtn);
    float* dst = mat ? c_img : c_txt;
    int tid = threadIdx.x;
    if (tid == 0) lcount = 0;
    __syncthreads();
    int base0 = slc * 1024;
    #pragma unroll
    for (int it = 0; it < 4; ++it) {
        int i  = base0 + it * 256 + tid;
        int lb = labels[i];
        if (lb == cls) { int s = atomicAdd(&lcount, 1); list[s] = i; }
    }
    __syncthreads();
    int m = lcount;
    if (m == 0) return;
    if (mat == 0 && tid == 0) atomicAdd(&cnt[cls], m);
    float a0 = 0.f, a1 = 0.f;
    int r = 0;
    for (; r + 4 <= m; r += 4) {               // 4 independent loads in flight
        unsigned u0 = src[(size_t)list[r]   * (DIM/2) + tid];
        unsigned u1 = src[(size_t)list[r+1] * (DIM/2) + tid];
        unsigned u2 = src[(size_t)list[r+2] * (DIM/2) + tid];
        unsigned u3 = src[(size_t)list[r+3] * (DIM/2) + tid];
        a0 += __uint_as_float((u0 & 0xffffu) << 16) + __uint_as_float((u1 & 0xffffu) << 16)
            + __uint_as_float((u2 & 0xffffu) << 16) + __uint_as_float((u3 & 0xffffu) << 16);
        a1 += __uint_as_float(u0 & 0xffff0000u) + __uint_as_float(u1 & 0xffff0000u)
            + __uint_as_float(u2 & 0xffff0000u) + __uint_as_float(u3 & 0xffff0000u);
    }
    for (; r < m; ++r) {
        unsigned u = src[(size_t)list[r] * (DIM/2) + tid];
        a0 += __uint_as_float((u & 0xffffu) << 16);
        a1 += __uint_as_float(u & 0xffff0000u);
    }
    unsafeAtomicAdd(&dst[(size_t)cls * DIM + tid*2],     a0);
    unsafeAtomicAdd(&dst[(size_t)cls * DIM + tid*2 + 1], a1);
}

// ---------------------------------------------------------------- fused GEMM
// S = scale*(img @ txt^T) once; epilogue accumulates ONLY exp sums.
// T4 pipeline: 3 LDS buffers, prefetch depth 2, counted s_waitcnt vmcnt(4)
// (never 0 in steady state) so staging loads stay in flight ACROSS barriers
// with two full K-steps of latency cover.
#define ASYNC16(gp, lp) \
  __builtin_amdgcn_global_load_lds((const __attribute__((address_space(1))) void*)(gp), \
                                   (__attribute__((address_space(3))) void*)(lp), 16, 0, 0)

#define SFENCE __builtin_amdgcn_sched_barrier(0)

#define STAGE(b, tcol, k0)                                                    \
  {                                                                           \
    const unsigned short* Ap = A + (size_t)(rowBase + w*16 + srow) * DIM      \
                                 + (k0) + spart;                              \
    const unsigned short* Bp = B + (size_t)((tcol) + w*16 + srow) * DIM       \
                                 + (k0) + spart;                              \
    ASYNC16(Ap,            &Ald[b][(w*16) * 32]);                             \
    ASYNC16(Ap + 64 * DIM, &Ald[b][(64 + w*16) * 32]);                        \
    ASYNC16(Bp,            &Bld[b][(w*16) * 32]);                             \
    ASYNC16(Bp + 64 * DIM, &Bld[b][(64 + w*16) * 32]);                        \
  }

__global__ __launch_bounds__(256, 3) void gemm_fused_kernel(
    const unsigned short* __restrict__ imgn, const unsigned short* __restrict__ txtn,
    float* __restrict__ rs, float* __restrict__ cs)
{
    __shared__ unsigned short Ald[3][BM * 32];
    __shared__ unsigned short Bld[3][BN * 32];
    __shared__ float red[2][BM];
    __shared__ float colb[2][CHUNK];      // [wr][col-in-chunk], written once each

    // natural order: consecutive bids share a chunk -> B panel stays L2-hot.
    int bid    = blockIdx.x;
    int rowblk = bid & 63;
    int chunk  = bid >> 6;
    const unsigned short* A = imgn;
    const unsigned short* B = txtn;
    int rowBase  = rowblk * BM;
    int colBase0 = chunk * CHUNK;

    int tid  = threadIdx.x;
    int lane = tid & 63;
    int w    = tid >> 6;
    int wr   = w >> 1, wc = w & 1;
    int q    = lane >> 4;
    int lm   = lane & 15;

    float s_acc[16];
    #pragma unroll
    for (int i = 0; i < 16; ++i) s_acc[i] = 0.f;

    int srow  = lane >> 2;        // staging: row within 16-row group
    int spart = (lane & 3) * 8;   // staging: k offset (elems)

    const float C1 = SCALE * LOG2E;
    const float C2 = -MAXLOGIT * LOG2E;

    // prologue: stage step 0 -> buf0, step 1 -> buf1; wait only for step 0.
    STAGE(0, colBase0, 0);
    STAGE(1, colBase0, 32);
    SFENCE;
    asm volatile("s_waitcnt vmcnt(4)" ::: "memory");
    SFENCE;
    __builtin_amdgcn_s_barrier();
    SFENCE;

    int bcur = 0;                 // buffer of the current step (g % 3)

    #pragma unroll 1
    for (int tile = 0; tile < CHUNK / BN; ++tile) {
        f32x4 acc[4][4];
        #pragma unroll
        for (int mi = 0; mi < 4; ++mi)
          #pragma unroll
          for (int ni = 0; ni < 4; ++ni)
            acc[mi][ni] = (f32x4){0.f, 0.f, 0.f, 0.f};

        #pragma unroll
        for (int kt = 0; kt < DIM / 32; ++kt) {
            // prefetch step g+2 into buf (bcur+2)%3 (readers of that buffer
            // finished at step g-1; its barrier already passed -> safe).
            int g2 = tile * 16 + kt + 2;
            if (g2 < 64) {
                int t2 = g2 >> 4, k2 = g2 & 15;
                int bpf = bcur + 2; if (bpf >= 3) bpf -= 3;
                STAGE(bpf, colBase0 + t2 * BN, k2 * 32);
            }

            short8 af[4], bf[4];
            #pragma unroll
            for (int mi = 0; mi < 4; ++mi)
                af[mi] = *(const short8*)(&Ald[bcur][(wr*64 + mi*16 + lm)*32 + q*8]);
            #pragma unroll
            for (int ni = 0; ni < 4; ++ni)
                bf[ni] = *(const short8*)(&Bld[bcur][(wc*64 + ni*16 + lm)*32 + q*8]);
            #pragma unroll
            for (int mi = 0; mi < 4; ++mi)
              #pragma unroll
              for (int ni = 0; ni < 4; ++ni)
                acc[mi][ni] = __builtin_amdgcn_mfma_f32_16x16x32_bf16(
                                  af[mi], bf[ni], acc[mi][ni], 0, 0, 0);

            // tile epilogue before the step wait: extra cover for prefetch.
            if (kt == DIM / 32 - 1) {
                #pragma unroll
                for (int ni = 0; ni < 4; ++ni) {
                    float csum = 0.f;
                    #pragma unroll
                    for (int mi = 0; mi < 4; ++mi) {
                      #pragma unroll
                      for (int r = 0; r < 4; ++r) {
                        float e = __builtin_amdgcn_exp2f(fmaf(acc[mi][ni][r], C1, C2));
                        s_acc[mi*4 + r] += e;
                        csum += e;
                      }
                    }
                    csum += __shfl_xor(csum, 16, 64);
                    csum += __shfl_xor(csum, 32, 64);
                    if (q == 0)
                        colb[wr][tile*BN + wc*64 + ni*16 + lm] = csum;
                }
            }

            // counted wait: the 4 newest outstanding loads are stage(g+2);
            // <=4 outstanding => stage(g+1) has landed. Tail steps drain.
            SFENCE;
            if (g2 < 64) asm volatile("s_waitcnt vmcnt(4)" ::: "memory");
            else         asm volatile("s_waitcnt vmcnt(0)" ::: "memory");
            SFENCE;
            __builtin_amdgcn_s_barrier();
            SFENCE;
            bcur = (bcur == 2) ? 0 : bcur + 1;
        }
    }

    // row stats: reduce across the 16 column-lanes (low 4 lane bits)
    #pragma unroll
    for (int idx = 0; idx < 16; ++idx) {
        float s = s_acc[idx];
        #pragma unroll
        for (int m = 1; m < 16; m <<= 1) s += __shfl_xor(s, m, 64);
        s_acc[idx] = s;
    }
    if (lm == 0) {
        #pragma unroll
        for (int idx = 0; idx < 16; ++idx) {
            int rl = wr*64 + (idx>>2)*16 + q*4 + (idx&3);
            red[wc][rl] = s_acc[idx];
        }
    }
    __syncthreads();
    if (tid < BM)
        unsafeAtomicAdd(&rs[rowBase + tid], red[0][tid] + red[1][tid]);
    for (int c = tid; c < CHUNK; c += 256)
        unsafeAtomicAdd(&cs[colBase0 + c], colb[0][c] + colb[1][c]);
}

// ---------------------------------------------------------------- final loss
// loss*2N = Sum_i (M + log rs_i) + Sum_i (M + log cs_i)
//           - 2*scale*[ Sum_l <c_img[l],c_txt[l]>/cnt_l + Sum_{lab=-1} <a_i,b_i> ]
__global__ __launch_bounds__(256) void loss_tail_kernel(
    const float* __restrict__ rs, const float* __restrict__ cs,
    const float* __restrict__ sd, const float* __restrict__ c_txt,
    const float* __restrict__ c_img, const int* __restrict__ cnt,
    float* __restrict__ out)
{
    __shared__ float wsum[4];
    int tid = threadIdx.x, lane = tid & 63, w = tid >> 6;
    int gidx = blockIdx.x * 256 + tid;           // 0..16383
    float local;
    if (gidx < N_ROWS)
        local = (MAXLOGIT + logf(rs[gidx])) - 2.0f * SCALE * sd[gidx];
    else
        local = MAXLOGIT + logf(cs[gidx - N_ROWS]);

    // class-dot portion: 2 classes per block, 4 dims per thread
    int cls = blockIdx.x * 2 + (tid >> 7);       // 0..127
    int e0  = (tid & 127) * 4;
    int n   = cnt[cls];
    if (n > 0) {
        float4 x = *(const float4*)(c_txt + (size_t)cls * DIM + e0);
        float4 y = *(const float4*)(c_img + (size_t)cls * DIM + e0);
        float dotp = x.x*y.x + x.y*y.y + x.z*y.z + x.w*y.w;
        local -= 2.0f * SCALE * dotp / (float)n;
    }

    #pragma unroll
    for (int m = 1; m < 64; m <<= 1) local += __shfl_xor(local, m, 64);
    if (lane == 0) wsum[w] = local;
    __syncthreads();
    if (tid == 0)
        unsafeAtomicAdd(out, (wsum[0] + wsum[1] + wsum[2] + wsum[3])
                             * (1.0f / (2 * N_ROWS)));
}

// ---------------------------------------------------------------- launch
extern "C" void kernel_launch(void* const* d_in, const int* in_sizes, int n_in,
                              void* d_out, int out_size, void* d_ws, size_t ws_size,
                              hipStream_t stream)
{
    const float* text   = (const float*)d_in[0];
    const float* image  = (const float*)d_in[1];
    const int*   labels = (const int*)d_in[2];

    unsigned short* imgn = (unsigned short*)d_ws;
    unsigned short* txtn = imgn + (size_t)N_ROWS * DIM;
    char* p = (char*)d_ws + 2 * (size_t)N_ROWS * DIM * sizeof(unsigned short);
    float* rs    = (float*)p;                       // 8192 f32  (zeroed)
    float* cs    = rs + N_ROWS;                     // 8192 f32  (zeroed)
    float* c_txt = cs + N_ROWS;                     // 128*512 f32 (zeroed)
    float* c_img = c_txt + (size_t)NCLS * DIM;      // 128*512 f32 (zeroed)
    int*   cnt   = (int*)(c_img + (size_t)NCLS * DIM); // 128 (zeroed)
    float* sd    = (float*)(cnt + NCLS);            // 8192 f32 (fully written)
    float* out = (float*)d_out;

    hipLaunchKernelGGL(norm_cast_kernel, dim3(N_ROWS / 4), dim3(256), 0, stream,
                       text, image, labels, imgn, txtn, (float4*)rs, sd, out);
    hipLaunchKernelGGL(gemm_fused_kernel, dim3(64 * NCHUNK), dim3(256), 0, stream,
                       imgn, txtn, rs, cs);
    hipLaunchKernelGGL(class_sum_kernel, dim3(16 * NCLS), dim3(256), 0, stream,
                       imgn, txtn, labels, c_txt, c_img, cnt);
    hipLaunchKernelGGL(loss_tail_kernel, dim3(64), dim3(256), 0, stream,
                       rs, cs, sd, c_txt, c_img, cnt, out);
}

// Round 7
// 171.034 us; speedup vs baseline: 1.3060x; 1.3060x over previous
//
#include <hip/hip_runtime.h>
#include <hip/hip_bf16.h>

#define N_ROWS 8192
#define DIM 512
#define SCALE 2.659f
#define MAXLOGIT 2.659f
#define LOG2E 1.4426950408889634f
#define NCHUNK 16
#define CHUNK 512
#define BM 128
#define BN 128
#define NCLS 128

typedef __attribute__((ext_vector_type(8))) short short8;
typedef __attribute__((ext_vector_type(4))) float f32x4;

// zero region: rs(8192) + cs(8192) + c_txt(65536) + c_img(65536) + cnt(128)
// = 147584 f32 = 36896 float4
#define ZERO_F4 36896

__device__ __forceinline__ unsigned short f2bf(float f) {
    unsigned int u = __float_as_uint(f);
    u += 0x7fffu + ((u >> 16) & 1u);
    return (unsigned short)(u >> 16);
}

// ---------------------------------------------------------------- normalize
// One wave handles image row i AND text row i: computes both norms, writes
// both bf16 rows, and emits the self-dot <a_i,b_i> (needed when label==-1).
// Also zero-initializes rs/cs/c_txt/c_img/cnt accumulators and out[0].
__global__ __launch_bounds__(256) void norm_cast_kernel(
    const float* __restrict__ text, const float* __restrict__ image,
    const int* __restrict__ labels,
    unsigned short* __restrict__ imgn, unsigned short* __restrict__ txtn,
    float4* __restrict__ zbase, float* __restrict__ sd, float* __restrict__ out)
{
    int zi = blockIdx.x * 256 + threadIdx.x;
    if (zi < ZERO_F4) zbase[zi] = make_float4(0.f, 0.f, 0.f, 0.f);
    if (zi == 0) out[0] = 0.f;

    int row  = blockIdx.x * 4 + (threadIdx.x >> 6);
    int lane = threadIdx.x & 63;
    const float4* si = (const float4*)(image + (size_t)row * DIM) + lane * 2;
    const float4* st = (const float4*)(text  + (size_t)row * DIM) + lane * 2;
    float4 a = si[0], b = si[1], c = st[0], d = st[1];
    float ssa = a.x*a.x + a.y*a.y + a.z*a.z + a.w*a.w
              + b.x*b.x + b.y*b.y + b.z*b.z + b.w*b.w;
    float sst = c.x*c.x + c.y*c.y + c.z*c.z + c.w*c.w
              + d.x*d.x + d.y*d.y + d.z*d.z + d.w*d.w;
    float sab = a.x*c.x + a.y*c.y + a.z*c.z + a.w*c.w
              + b.x*d.x + b.y*d.y + b.z*d.z + b.w*d.w;
    #pragma unroll
    for (int m = 1; m < 64; m <<= 1) {
        ssa += __shfl_xor(ssa, m, 64);
        sst += __shfl_xor(sst, m, 64);
        sab += __shfl_xor(sab, m, 64);
    }
    float sca = 1.0f / fmaxf(sqrtf(ssa), 1e-12f);
    float sct = 1.0f / fmaxf(sqrtf(sst), 1e-12f);
    uint4 oi, ot;
    oi.x = (unsigned)f2bf(a.x*sca) | ((unsigned)f2bf(a.y*sca) << 16);
    oi.y = (unsigned)f2bf(a.z*sca) | ((unsigned)f2bf(a.w*sca) << 16);
    oi.z = (unsigned)f2bf(b.x*sca) | ((unsigned)f2bf(b.y*sca) << 16);
    oi.w = (unsigned)f2bf(b.z*sca) | ((unsigned)f2bf(b.w*sca) << 16);
    ot.x = (unsigned)f2bf(c.x*sct) | ((unsigned)f2bf(c.y*sct) << 16);
    ot.y = (unsigned)f2bf(c.z*sct) | ((unsigned)f2bf(c.w*sct) << 16);
    ot.z = (unsigned)f2bf(d.x*sct) | ((unsigned)f2bf(d.y*sct) << 16);
    ot.w = (unsigned)f2bf(d.z*sct) | ((unsigned)f2bf(d.w*sct) << 16);
    *((uint4*)(imgn + (size_t)row * DIM) + lane) = oi;
    *((uint4*)(txtn + (size_t)row * DIM) + lane) = ot;
    if (lane == 0)
        sd[row] = (labels[row] < 0) ? sab * sca * sct : 0.0f;
}

// ---------------------------------------------------------------- class sums
// 2048 blocks = (8 label-slices) x (128 classes) x (2 matrices). Each block
// scans 1K labels, gathers its ~10 matching rows, atomically accumulates
// into c_txt/c_img (f32, zeroed by norm_cast) and cnt.
__global__ __launch_bounds__(256) void class_sum_kernel(
    const unsigned short* __restrict__ imgn, const unsigned short* __restrict__ txtn,
    const int* __restrict__ labels,
    float* __restrict__ c_txt, float* __restrict__ c_img, int* __restrict__ cnt)
{
    __shared__ int list[1024];
    __shared__ int lcount;
    int blk = blockIdx.x;
    int cls = blk & (NCLS - 1);
    int mat = (blk >> 7) & 1;                  // 0: txt sums, 1: img sums
    int slc = blk >> 8;                        // 0..7
    const unsigned* src = (const unsigned*)(mat ? imgn : txtn);
    float* dst = mat ? c_img : c_txt;
    int tid = threadIdx.x;
    if (tid == 0) lcount = 0;
    __syncthreads();
    int base0 = slc * 1024;
    #pragma unroll
    for (int it = 0; it < 4; ++it) {
        int i  = base0 + it * 256 + tid;
        int lb = labels[i];
        if (lb == cls) { int s = atomicAdd(&lcount, 1); list[s] = i; }
    }
    __syncthreads();
    int m = lcount;
    if (m == 0) return;
    if (mat == 0 && tid == 0) atomicAdd(&cnt[cls], m);
    float a0 = 0.f, a1 = 0.f;
    int r = 0;
    for (; r + 4 <= m; r += 4) {               // 4 independent loads in flight
        unsigned u0 = src[(size_t)list[r]   * (DIM/2) + tid];
        unsigned u1 = src[(size_t)list[r+1] * (DIM/2) + tid];
        unsigned u2 = src[(size_t)list[r+2] * (DIM/2) + tid];
        unsigned u3 = src[(size_t)list[r+3] * (DIM/2) + tid];
        a0 += __uint_as_float((u0 & 0xffffu) << 16) + __uint_as_float((u1 & 0xffffu) << 16)
            + __uint_as_float((u2 & 0xffffu) << 16) + __uint_as_float((u3 & 0xffffu) << 16);
        a1 += __uint_as_float(u0 & 0xffff0000u) + __uint_as_float(u1 & 0xffff0000u)
            + __uint_as_float(u2 & 0xffff0000u) + __uint_as_float(u3 & 0xffff0000u);
    }
    for (; r < m; ++r) {
        unsigned u = src[(size_t)list[r] * (DIM/2) + tid];
        a0 += __uint_as_float((u & 0xffffu) << 16);
        a1 += __uint_as_float(u & 0xffff0000u);
    }
    unsafeAtomicAdd(&dst[(size_t)cls * DIM + tid*2],     a0);
    unsafeAtomicAdd(&dst[(size_t)cls * DIM + tid*2 + 1], a1);
}

// ---------------------------------------------------------------- fused GEMM
// S = scale*(img @ txt^T) once; epilogue accumulates ONLY exp sums.
// T4 pipeline, spill-safe: 4 LDS buffers (buffer index = step&3, fully
// static after kt-unroll), prefetch depth 2, counted s_waitcnt vmcnt(4)
// in steady state (wait-then-barrier => cross-wave completion of stage g+1),
// launch_bounds(256,2) so VGPR+AGPR (~176 unified) fits without spilling.
#define ASYNC16(gp, lp) \
  __builtin_amdgcn_global_load_lds((const __attribute__((address_space(1))) void*)(gp), \
                                   (__attribute__((address_space(3))) void*)(lp), 16, 0, 0)

#define SFENCE __builtin_amdgcn_sched_barrier(0)

#define STAGE(b, tcol, k0)                                                    \
  {                                                                           \
    const unsigned short* Ap = A + (size_t)(rowBase + w*16 + srow) * DIM      \
                                 + (k0) + spart;                              \
    const unsigned short* Bp = B + (size_t)((tcol) + w*16 + srow) * DIM       \
                                 + (k0) + spart;                              \
    ASYNC16(Ap,            &Ald[b][(w*16) * 32]);                             \
    ASYNC16(Ap + 64 * DIM, &Ald[b][(64 + w*16) * 32]);                        \
    ASYNC16(Bp,            &Bld[b][(w*16) * 32]);                             \
    ASYNC16(Bp + 64 * DIM, &Bld[b][(64 + w*16) * 32]);                        \
  }

__global__ __launch_bounds__(256, 2) void gemm_fused_kernel(
    const unsigned short* __restrict__ imgn, const unsigned short* __restrict__ txtn,
    float* __restrict__ rs, float* __restrict__ cs)
{
    __shared__ unsigned short Ald[4][BM * 32];
    __shared__ unsigned short Bld[4][BN * 32];
    __shared__ float red[2][BM];
    __shared__ float colb[2][CHUNK];      // [wr][col-in-chunk], written once each

    // natural order: consecutive bids share a chunk -> B panel stays L2-hot.
    int bid    = blockIdx.x;
    int rowblk = bid & 63;
    int chunk  = bid >> 6;
    const unsigned short* A = imgn;
    const unsigned short* B = txtn;
    int rowBase  = rowblk * BM;
    int colBase0 = chunk * CHUNK;

    int tid  = threadIdx.x;
    int lane = tid & 63;
    int w    = tid >> 6;
    int wr   = w >> 1, wc = w & 1;
    int q    = lane >> 4;
    int lm   = lane & 15;

    float s_acc[16];
    #pragma unroll
    for (int i = 0; i < 16; ++i) s_acc[i] = 0.f;

    int srow  = lane >> 2;        // staging: row within 16-row group
    int spart = (lane & 3) * 8;   // staging: k offset (elems)

    const float C1 = SCALE * LOG2E;
    const float C2 = -MAXLOGIT * LOG2E;

    // prologue: stage step 0 -> buf0, step 1 -> buf1; wait only for step 0.
    STAGE(0, colBase0, 0);
    STAGE(1, colBase0, 32);
    SFENCE;
    asm volatile("s_waitcnt vmcnt(4)" ::: "memory");
    SFENCE;
    __builtin_amdgcn_s_barrier();
    SFENCE;

    #pragma unroll 1
    for (int tile = 0; tile < CHUNK / BN; ++tile) {
        f32x4 acc[4][4];
        #pragma unroll
        for (int mi = 0; mi < 4; ++mi)
          #pragma unroll
          for (int ni = 0; ni < 4; ++ni)
            acc[mi][ni] = (f32x4){0.f, 0.f, 0.f, 0.f};

        #pragma unroll
        for (int kt = 0; kt < DIM / 32; ++kt) {
            // step index g = tile*16 + kt; tile*16 % 4 == 0, so after the
            // kt-unroll every buffer index below is a compile-time constant.
            const int bcur = kt & 3;          // g & 3
            const int bpf  = (kt + 2) & 3;    // (g+2) & 3
            // prefetch step g+2 (readers of that buffer finished at step
            // g-2; two barriers have passed -> safe).
            int g2 = tile * 16 + kt + 2;
            if (g2 < 64) {
                int t2 = g2 >> 4, k2 = g2 & 15;
                STAGE(bpf, colBase0 + t2 * BN, k2 * 32);
            }

            short8 af[4], bf[4];
            #pragma unroll
            for (int mi = 0; mi < 4; ++mi)
                af[mi] = *(const short8*)(&Ald[bcur][(wr*64 + mi*16 + lm)*32 + q*8]);
            #pragma unroll
            for (int ni = 0; ni < 4; ++ni)
                bf[ni] = *(const short8*)(&Bld[bcur][(wc*64 + ni*16 + lm)*32 + q*8]);
            #pragma unroll
            for (int mi = 0; mi < 4; ++mi)
              #pragma unroll
              for (int ni = 0; ni < 4; ++ni)
                acc[mi][ni] = __builtin_amdgcn_mfma_f32_16x16x32_bf16(
                                  af[mi], bf[ni], acc[mi][ni], 0, 0, 0);

            // tile epilogue before the step wait: extra cover for prefetch.
            if (kt == DIM / 32 - 1) {
                #pragma unroll
                for (int ni = 0; ni < 4; ++ni) {
                    float csum = 0.f;
                    #pragma unroll
                    for (int mi = 0; mi < 4; ++mi) {
                      #pragma unroll
                      for (int r = 0; r < 4; ++r) {
                        float e = __builtin_amdgcn_exp2f(fmaf(acc[mi][ni][r], C1, C2));
                        s_acc[mi*4 + r] += e;
                        csum += e;
                      }
                    }
                    csum += __shfl_xor(csum, 16, 64);
                    csum += __shfl_xor(csum, 32, 64);
                    if (q == 0)
                        colb[wr][tile*BN + wc*64 + ni*16 + lm] = csum;
                }
            }

            // counted wait: the 4 newest outstanding loads are stage(g+2);
            // <=4 outstanding => stage(g+1) landed. Then barrier => ALL
            // waves' stage(g+1) landed before anyone enters step g+1.
            // Tail steps (no stage issued) drain fully.
            SFENCE;
            if (g2 < 64) asm volatile("s_waitcnt vmcnt(4)" ::: "memory");
            else         asm volatile("s_waitcnt vmcnt(0)" ::: "memory");
            SFENCE;
            __builtin_amdgcn_s_barrier();
            SFENCE;
        }
    }

    // row stats: reduce across the 16 column-lanes (low 4 lane bits)
    #pragma unroll
    for (int idx = 0; idx < 16; ++idx) {
        float s = s_acc[idx];
        #pragma unroll
        for (int m = 1; m < 16; m <<= 1) s += __shfl_xor(s, m, 64);
        s_acc[idx] = s;
    }
    if (lm == 0) {
        #pragma unroll
        for (int idx = 0; idx < 16; ++idx) {
            int rl = wr*64 + (idx>>2)*16 + q*4 + (idx&3);
            red[wc][rl] = s_acc[idx];
        }
    }
    __syncthreads();
    if (tid < BM)
        unsafeAtomicAdd(&rs[rowBase + tid], red[0][tid] + red[1][tid]);
    for (int c = tid; c < CHUNK; c += 256)
        unsafeAtomicAdd(&cs[colBase0 + c], colb[0][c] + colb[1][c]);
}

// ---------------------------------------------------------------- final loss
// loss*2N = Sum_i (M + log rs_i) + Sum_i (M + log cs_i)
//           - 2*scale*[ Sum_l <c_img[l],c_txt[l]>/cnt_l + Sum_{lab=-1} <a_i,b_i> ]
__global__ __launch_bounds__(256) void loss_tail_kernel(
    const float* __restrict__ rs, const float* __restrict__ cs,
    const float* __restrict__ sd, const float* __restrict__ c_txt,
    const float* __restrict__ c_img, const int* __restrict__ cnt,
    float* __restrict__ out)
{
    __shared__ float wsum[4];
    int tid = threadIdx.x, lane = tid & 63, w = tid >> 6;
    int gidx = blockIdx.x * 256 + tid;           // 0..16383
    float local;
    if (gidx < N_ROWS)
        local = (MAXLOGIT + logf(rs[gidx])) - 2.0f * SCALE * sd[gidx];
    else
        local = MAXLOGIT + logf(cs[gidx - N_ROWS]);

    // class-dot portion: 2 classes per block, 4 dims per thread
    int cls = blockIdx.x * 2 + (tid >> 7);       // 0..127
    int e0  = (tid & 127) * 4;
    int n   = cnt[cls];
    if (n > 0) {
        float4 x = *(const float4*)(c_txt + (size_t)cls * DIM + e0);
        float4 y = *(const float4*)(c_img + (size_t)cls * DIM + e0);
        float dotp = x.x*y.x + x.y*y.y + x.z*y.z + x.w*y.w;
        local -= 2.0f * SCALE * dotp / (float)n;
    }

    #pragma unroll
    for (int m = 1; m < 64; m <<= 1) local += __shfl_xor(local, m, 64);
    if (lane == 0) wsum[w] = local;
    __syncthreads();
    if (tid == 0)
        unsafeAtomicAdd(out, (wsum[0] + wsum[1] + wsum[2] + wsum[3])
                             * (1.0f / (2 * N_ROWS)));
}

// ---------------------------------------------------------------- launch
extern "C" void kernel_launch(void* const* d_in, const int* in_sizes, int n_in,
                              void* d_out, int out_size, void* d_ws, size_t ws_size,
                              hipStream_t stream)
{
    const float* text   = (const float*)d_in[0];
    const float* image  = (const float*)d_in[1];
    const int*   labels = (const int*)d_in[2];

    unsigned short* imgn = (unsigned short*)d_ws;
    unsigned short* txtn = imgn + (size_t)N_ROWS * DIM;
    char* p = (char*)d_ws + 2 * (size_t)N_ROWS * DIM * sizeof(unsigned short);
    float* rs    = (float*)p;                       // 8192 f32  (zeroed)
    float* cs    = rs + N_ROWS;                     // 8192 f32  (zeroed)
    float* c_txt = cs + N_ROWS;                     // 128*512 f32 (zeroed)
    float* c_img = c_txt + (size_t)NCLS * DIM;      // 128*512 f32 (zeroed)
    int*   cnt   = (int*)(c_img + (size_t)NCLS * DIM); // 128 (zeroed)
    float* sd    = (float*)(cnt + NCLS);            // 8192 f32 (fully written)
    float* out = (float*)d_out;

    hipLaunchKernelGGL(norm_cast_kernel, dim3(N_ROWS / 4), dim3(256), 0, stream,
                       text, image, labels, imgn, txtn, (float4*)rs, sd, out);
    hipLaunchKernelGGL(gemm_fused_kernel, dim3(64 * NCHUNK), dim3(256), 0, stream,
                       imgn, txtn, rs, cs);
    hipLaunchKernelGGL(class_sum_kernel, dim3(16 * NCLS), dim3(256), 0, stream,
                       imgn, txtn, labels, c_txt, c_img, cnt);
    hipLaunchKernelGGL(loss_tail_kernel, dim3(64), dim3(256), 0, stream,
                       rs, cs, sd, c_txt, c_img, cnt, out);
}

// Round 8
// 168.188 us; speedup vs baseline: 1.3281x; 1.0169x over previous
//
#include <hip/hip_runtime.h>
#include <hip/hip_bf16.h>

#define N_ROWS 8192
#define DIM 512
#define SCALE 2.659f
#define MAXLOGIT 2.659f
#define LOG2E 1.4426950408889634f
#define BM 256
#define BN 256
#define NCLS 128
#define GEMM_BLKS 1024   // (8192/256)^2

typedef __attribute__((ext_vector_type(8))) short short8;
typedef __attribute__((ext_vector_type(4))) float f32x4;

// zero region: rs(8192) + cs(8192) + c_txt(65536) + c_img(65536) + cnt(128)
// = 147584 f32 = 36896 float4
#define ZERO_F4 36896

__device__ __forceinline__ unsigned short f2bf(float f) {
    unsigned int u = __float_as_uint(f);
    u += 0x7fffu + ((u >> 16) & 1u);
    return (unsigned short)(u >> 16);
}

// ---------------------------------------------------------------- normalize
// One wave handles image row i AND text row i: computes both norms, writes
// both bf16 rows, and emits the self-dot <a_i,b_i> (needed when label==-1).
// Also zero-initializes rs/cs/c_txt/c_img/cnt accumulators and out[0].
__global__ __launch_bounds__(256) void norm_cast_kernel(
    const float* __restrict__ text, const float* __restrict__ image,
    const int* __restrict__ labels,
    unsigned short* __restrict__ imgn, unsigned short* __restrict__ txtn,
    float4* __restrict__ zbase, float* __restrict__ sd, float* __restrict__ out)
{
    int zi = blockIdx.x * 256 + threadIdx.x;
    if (zi < ZERO_F4) zbase[zi] = make_float4(0.f, 0.f, 0.f, 0.f);
    if (zi == 0) out[0] = 0.f;

    int row  = blockIdx.x * 4 + (threadIdx.x >> 6);
    int lane = threadIdx.x & 63;
    const float4* si = (const float4*)(image + (size_t)row * DIM) + lane * 2;
    const float4* st = (const float4*)(text  + (size_t)row * DIM) + lane * 2;
    float4 a = si[0], b = si[1], c = st[0], d = st[1];
    float ssa = a.x*a.x + a.y*a.y + a.z*a.z + a.w*a.w
              + b.x*b.x + b.y*b.y + b.z*b.z + b.w*b.w;
    float sst = c.x*c.x + c.y*c.y + c.z*c.z + c.w*c.w
              + d.x*d.x + d.y*d.y + d.z*d.z + d.w*d.w;
    float sab = a.x*c.x + a.y*c.y + a.z*c.z + a.w*c.w
              + b.x*d.x + b.y*d.y + b.z*d.z + b.w*d.w;
    #pragma unroll
    for (int m = 1; m < 64; m <<= 1) {
        ssa += __shfl_xor(ssa, m, 64);
        sst += __shfl_xor(sst, m, 64);
        sab += __shfl_xor(sab, m, 64);
    }
    float sca = 1.0f / fmaxf(sqrtf(ssa), 1e-12f);
    float sct = 1.0f / fmaxf(sqrtf(sst), 1e-12f);
    uint4 oi, ot;
    oi.x = (unsigned)f2bf(a.x*sca) | ((unsigned)f2bf(a.y*sca) << 16);
    oi.y = (unsigned)f2bf(a.z*sca) | ((unsigned)f2bf(a.w*sca) << 16);
    oi.z = (unsigned)f2bf(b.x*sca) | ((unsigned)f2bf(b.y*sca) << 16);
    oi.w = (unsigned)f2bf(b.z*sca) | ((unsigned)f2bf(b.w*sca) << 16);
    ot.x = (unsigned)f2bf(c.x*sct) | ((unsigned)f2bf(c.y*sct) << 16);
    ot.y = (unsigned)f2bf(c.z*sct) | ((unsigned)f2bf(c.w*sct) << 16);
    ot.z = (unsigned)f2bf(d.x*sct) | ((unsigned)f2bf(d.y*sct) << 16);
    ot.w = (unsigned)f2bf(d.z*sct) | ((unsigned)f2bf(d.w*sct) << 16);
    *((uint4*)(imgn + (size_t)row * DIM) + lane) = oi;
    *((uint4*)(txtn + (size_t)row * DIM) + lane) = ot;
    if (lane == 0)
        sd[row] = (labels[row] < 0) ? sab * sca * sct : 0.0f;
}

// ---------------------------------------------------------------- fused GEMM
// Blocks [0, GEMM_BLKS): 256x256 output tile of S = scale*(img @ txt^T),
//   epilogue accumulates exp-sums (row + col) only. d-terms are algebraic
//   (class sums), handled by the class blocks + loss_tail.
// Blocks [GEMM_BLKS, GEMM_BLKS+256): class-sum path (one block per
//   (class, matrix)), fused here to save a launch and overlap the tail.
// Sync skeleton (verified round 7): 4 LDS buffers (index = step&3, static
// after unroll), prefetch depth 2, counted s_waitcnt vmcnt(4) steady state,
// wait-then-barrier; tail steps drain.
#define ASYNC16(gp, lp) \
  __builtin_amdgcn_global_load_lds((const __attribute__((address_space(1))) void*)(gp), \
                                   (__attribute__((address_space(3))) void*)(lp), 16, 0, 0)

#define SFENCE __builtin_amdgcn_sched_barrier(0)

// 512 threads stage a 256x32 K-slice of A and B: wave w covers rows
// w*16..w*16+15 and 128+w*16..128+w*16+15 of each (lane l -> row l>>2,
// elems (l&3)*8, matching global_load_lds's base + lane*16B layout).
#define STAGE(b, k0)                                                          \
  {                                                                           \
    const unsigned short* Ap = A + (size_t)(rowBase + w*16 + srow) * DIM      \
                                 + (k0) + spart;                              \
    const unsigned short* Bp = B + (size_t)(colBase + w*16 + srow) * DIM      \
                                 + (k0) + spart;                              \
    ASYNC16(Ap,             &Ald[b][(w*16) * 32]);                            \
    ASYNC16(Ap + 128 * DIM, &Ald[b][(128 + w*16) * 32]);                      \
    ASYNC16(Bp,             &Bld[b][(w*16) * 32]);                            \
    ASYNC16(Bp + 128 * DIM, &Bld[b][(128 + w*16) * 32]);                      \
  }

__global__ __launch_bounds__(512, 2) void gemm_fused_kernel(
    const unsigned short* __restrict__ imgn, const unsigned short* __restrict__ txtn,
    const int* __restrict__ labels,
    float* __restrict__ rs, float* __restrict__ cs,
    float* __restrict__ c_txt, float* __restrict__ c_img, int* __restrict__ cnt)
{
    __shared__ unsigned short Ald[4][BM * 32];   // 64 KB
    __shared__ unsigned short Bld[4][BN * 32];   // 64 KB
    __shared__ float red[4][BM];                 // 4 KB  [wc][row-in-tile]
    __shared__ float colb[2][BN];                // 2 KB  [wr][col-in-tile]
    __shared__ int   list[1024];                 // 4 KB  (class path)
    __shared__ int   lcount;

    int tid  = threadIdx.x;

    // ---------------- class-sum path ----------------
    if (blockIdx.x >= GEMM_BLKS) {
        int blk = blockIdx.x - GEMM_BLKS;
        int cls = blk & (NCLS - 1);
        int mat = blk >> 7;                    // 0: txt sums, 1: img sums
        const unsigned* src = (const unsigned*)(mat ? imgn : txtn);
        float* dst = mat ? c_img : c_txt;
        if (tid == 0) lcount = 0;
        __syncthreads();
        #pragma unroll
        for (int base = 0; base < N_ROWS; base += 512) {
            int lb = labels[base + tid];
            if (lb == cls) { int s = atomicAdd(&lcount, 1); list[s & 1023] = base + tid; }
        }
        __syncthreads();
        int m = lcount;
        if (mat == 0 && tid == 0) cnt[cls] = m;
        int half = tid >> 8;                   // two thread-halves split rows
        int col  = tid & 255;                  // u32 column (2 bf16)
        float a0 = 0.f, a1 = 0.f;
        int r = half;
        for (; r + 6 < m; r += 8) {            // 4 independent loads in flight
            unsigned u0 = src[(size_t)list[r]   * (DIM/2) + col];
            unsigned u1 = src[(size_t)list[r+2] * (DIM/2) + col];
            unsigned u2 = src[(size_t)list[r+4] * (DIM/2) + col];
            unsigned u3 = src[(size_t)list[r+6] * (DIM/2) + col];
            a0 += __uint_as_float((u0 & 0xffffu) << 16) + __uint_as_float((u1 & 0xffffu) << 16)
                + __uint_as_float((u2 & 0xffffu) << 16) + __uint_as_float((u3 & 0xffffu) << 16);
            a1 += __uint_as_float(u0 & 0xffff0000u) + __uint_as_float(u1 & 0xffff0000u)
                + __uint_as_float(u2 & 0xffff0000u) + __uint_as_float(u3 & 0xffff0000u);
        }
        for (; r < m; r += 2) {
            unsigned u = src[(size_t)list[r] * (DIM/2) + col];
            a0 += __uint_as_float((u & 0xffffu) << 16);
            a1 += __uint_as_float(u & 0xffff0000u);
        }
        if (a0 != 0.f || a1 != 0.f) {
            unsafeAtomicAdd(&dst[(size_t)cls * DIM + col*2],     a0);
            unsafeAtomicAdd(&dst[(size_t)cls * DIM + col*2 + 1], a1);
        }
        return;
    }

    // ---------------- GEMM path ----------------
    int bid    = blockIdx.x;
    int rowblk = bid & 31;
    int colblk = bid >> 5;        // consecutive bids share colblk -> B L2-hot
    const unsigned short* A = imgn;
    const unsigned short* B = txtn;
    int rowBase = rowblk * BM;
    int colBase = colblk * BN;

    int lane = tid & 63;
    int w    = tid >> 6;          // 0..7
    int wr   = w >> 2, wc = w & 3;
    int q    = lane >> 4;
    int lm   = lane & 15;

    int srow  = lane >> 2;        // staging: row within 16-row group
    int spart = (lane & 3) * 8;   // staging: k offset (elems)

    const float C1 = SCALE * LOG2E;
    const float C2 = -MAXLOGIT * LOG2E;

    f32x4 acc[8][4];
    #pragma unroll
    for (int mi = 0; mi < 8; ++mi)
      #pragma unroll
      for (int ni = 0; ni < 4; ++ni)
        acc[mi][ni] = (f32x4){0.f, 0.f, 0.f, 0.f};

    // prologue: stage step 0 -> buf0, step 1 -> buf1; wait only for step 0.
    STAGE(0, 0);
    STAGE(1, 32);
    SFENCE;
    asm volatile("s_waitcnt vmcnt(4)" ::: "memory");
    SFENCE;
    __builtin_amdgcn_s_barrier();
    SFENCE;

    #pragma unroll
    for (int g = 0; g < DIM / 32; ++g) {       // 16 K-steps, one tile
        const int bcur = g & 3;
        const int bpf  = (g + 2) & 3;
        if (g + 2 < DIM / 32) {
            STAGE(bpf, (g + 2) * 32);          // prefetch depth 2
        }

        short8 af[8], bf[4];
        #pragma unroll
        for (int mi = 0; mi < 8; ++mi)
            af[mi] = *(const short8*)(&Ald[bcur][(wr*128 + mi*16 + lm)*32 + q*8]);
        #pragma unroll
        for (int ni = 0; ni < 4; ++ni)
            bf[ni] = *(const short8*)(&Bld[bcur][(wc*64 + ni*16 + lm)*32 + q*8]);
        #pragma unroll
        for (int mi = 0; mi < 8; ++mi)
          #pragma unroll
          for (int ni = 0; ni < 4; ++ni)
            acc[mi][ni] = __builtin_amdgcn_mfma_f32_16x16x32_bf16(
                              af[mi], bf[ni], acc[mi][ni], 0, 0, 0);

        // counted wait: the 4 newest outstanding loads are stage(g+2);
        // <=4 outstanding => stage(g+1) landed. Then barrier => ALL waves'
        // stage(g+1) landed before anyone enters step g+1. Tail drains.
        SFENCE;
        if (g + 2 < DIM / 32) asm volatile("s_waitcnt vmcnt(4)" ::: "memory");
        else                  asm volatile("s_waitcnt vmcnt(0)" ::: "memory");
        SFENCE;
        __builtin_amdgcn_s_barrier();
        SFENCE;
    }

    // epilogue: one exp per S element serves BOTH loss directions.
    float rsum[32];
    #pragma unroll
    for (int i = 0; i < 32; ++i) rsum[i] = 0.f;
    #pragma unroll
    for (int ni = 0; ni < 4; ++ni) {
        float csum = 0.f;
        #pragma unroll
        for (int mi = 0; mi < 8; ++mi) {
          #pragma unroll
          for (int r = 0; r < 4; ++r) {
            float e = __builtin_amdgcn_exp2f(fmaf(acc[mi][ni][r], C1, C2));
            rsum[mi*4 + r] += e;
            csum += e;
          }
        }
        csum += __shfl_xor(csum, 16, 64);      // reduce over q (lane bits 4,5)
        csum += __shfl_xor(csum, 32, 64);
        if (q == 0)
            colb[wr][wc*64 + ni*16 + lm] = csum;
    }
    // row sums: reduce across the 16 column-lanes (low 4 lane bits)
    #pragma unroll
    for (int idx = 0; idx < 32; ++idx) {
        float s = rsum[idx];
        #pragma unroll
        for (int m = 1; m < 16; m <<= 1) s += __shfl_xor(s, m, 64);
        if (lm == 0)
            red[wc][wr*128 + (idx>>2)*16 + q*4 + (idx&3)] = s;
    }
    __syncthreads();
    if (tid < BM) {
        unsafeAtomicAdd(&rs[rowBase + tid],
                        red[0][tid] + red[1][tid] + red[2][tid] + red[3][tid]);
        unsafeAtomicAdd(&cs[colBase + tid], colb[0][tid] + colb[1][tid]);
    }
}

// ---------------------------------------------------------------- final loss
// loss*2N = Sum_i (M + log rs_i) + Sum_i (M + log cs_i)
//           - 2*scale*[ Sum_l <c_img[l],c_txt[l]>/cnt_l + Sum_{lab=-1} <a_i,b_i> ]
__global__ __launch_bounds__(256) void loss_tail_kernel(
    const float* __restrict__ rs, const float* __restrict__ cs,
    const float* __restrict__ sd, const float* __restrict__ c_txt,
    const float* __restrict__ c_img, const int* __restrict__ cnt,
    float* __restrict__ out)
{
    __shared__ float wsum[4];
    int tid = threadIdx.x, lane = tid & 63, w = tid >> 6;
    int gidx = blockIdx.x * 256 + tid;           // 0..16383
    float local;
    if (gidx < N_ROWS)
        local = (MAXLOGIT + logf(rs[gidx])) - 2.0f * SCALE * sd[gidx];
    else
        local = MAXLOGIT + logf(cs[gidx - N_ROWS]);

    // class-dot portion: 2 classes per block, 4 dims per thread
    int cls = blockIdx.x * 2 + (tid >> 7);       // 0..127
    int e0  = (tid & 127) * 4;
    int n   = cnt[cls];
    if (n > 0) {
        float4 x = *(const float4*)(c_txt + (size_t)cls * DIM + e0);
        float4 y = *(const float4*)(c_img + (size_t)cls * DIM + e0);
        float dotp = x.x*y.x + x.y*y.y + x.z*y.z + x.w*y.w;
        local -= 2.0f * SCALE * dotp / (float)n;
    }

    #pragma unroll
    for (int m = 1; m < 64; m <<= 1) local += __shfl_xor(local, m, 64);
    if (lane == 0) wsum[w] = local;
    __syncthreads();
    if (tid == 0)
        unsafeAtomicAdd(out, (wsum[0] + wsum[1] + wsum[2] + wsum[3])
                             * (1.0f / (2 * N_ROWS)));
}

// ---------------------------------------------------------------- launch
extern "C" void kernel_launch(void* const* d_in, const int* in_sizes, int n_in,
                              void* d_out, int out_size, void* d_ws, size_t ws_size,
                              hipStream_t stream)
{
    const float* text   = (const float*)d_in[0];
    const float* image  = (const float*)d_in[1];
    const int*   labels = (const int*)d_in[2];

    unsigned short* imgn = (unsigned short*)d_ws;
    unsigned short* txtn = imgn + (size_t)N_ROWS * DIM;
    char* p = (char*)d_ws + 2 * (size_t)N_ROWS * DIM * sizeof(unsigned short);
    float* rs    = (float*)p;                       // 8192 f32  (zeroed)
    float* cs    = rs + N_ROWS;                     // 8192 f32  (zeroed)
    float* c_txt = cs + N_ROWS;                     // 128*512 f32 (zeroed)
    float* c_img = c_txt + (size_t)NCLS * DIM;      // 128*512 f32 (zeroed)
    int*   cnt   = (int*)(c_img + (size_t)NCLS * DIM); // 128 (zeroed)
    float* sd    = (float*)(cnt + NCLS);            // 8192 f32 (fully written)
    float* out = (float*)d_out;

    hipLaunchKernelGGL(norm_cast_kernel, dim3(N_ROWS / 4), dim3(256), 0, stream,
                       text, image, labels, imgn, txtn, (float4*)rs, sd, out);
    hipLaunchKernelGGL(gemm_fused_kernel, dim3(GEMM_BLKS + 2 * NCLS), dim3(512), 0, stream,
                       imgn, txtn, labels, rs, cs, c_txt, c_img, cnt);
    hipLaunchKernelGGL(loss_tail_kernel, dim3(64), dim3(256), 0, stream,
                       rs, cs, sd, c_txt, c_img, cnt, out);
}

// Round 9
// 166.960 us; speedup vs baseline: 1.3379x; 1.0074x over previous
//
#include <hip/hip_runtime.h>
#include <hip/hip_bf16.h>

#define N_ROWS 8192
#define DIM 512
#define SCALE 2.659f
#define MAXLOGIT 2.659f
#define LOG2E 1.4426950408889634f
#define NCHUNK 16
#define CHUNK 512
#define BM 128
#define BN 128
#define NCLS 128
#define GEMM_BLKS 1024   // 64 rowblks x 16 chunks

typedef __attribute__((ext_vector_type(8))) short short8;
typedef __attribute__((ext_vector_type(4))) float f32x4;

// zero region: rs(8192) + cs(8192) + c_txt(65536) + c_img(65536) + cnt(128)
// = 147584 f32 = 36896 float4
#define ZERO_F4 36896

__device__ __forceinline__ unsigned short f2bf(float f) {
    unsigned int u = __float_as_uint(f);
    u += 0x7fffu + ((u >> 16) & 1u);
    return (unsigned short)(u >> 16);
}

// ---------------------------------------------------------------- normalize
// One wave handles image row i AND text row i: computes both norms, writes
// both bf16 rows, and emits the self-dot <a_i,b_i> (needed when label==-1).
// Also zero-initializes rs/cs/c_txt/c_img/cnt accumulators and out[0].
__global__ __launch_bounds__(256) void norm_cast_kernel(
    const float* __restrict__ text, const float* __restrict__ image,
    const int* __restrict__ labels,
    unsigned short* __restrict__ imgn, unsigned short* __restrict__ txtn,
    float4* __restrict__ zbase, float* __restrict__ sd, float* __restrict__ out)
{
    int zi = blockIdx.x * 256 + threadIdx.x;
    if (zi < ZERO_F4) zbase[zi] = make_float4(0.f, 0.f, 0.f, 0.f);
    if (zi == 0) out[0] = 0.f;

    int row  = blockIdx.x * 4 + (threadIdx.x >> 6);
    int lane = threadIdx.x & 63;
    const float4* si = (const float4*)(image + (size_t)row * DIM) + lane * 2;
    const float4* st = (const float4*)(text  + (size_t)row * DIM) + lane * 2;
    float4 a = si[0], b = si[1], c = st[0], d = st[1];
    float ssa = a.x*a.x + a.y*a.y + a.z*a.z + a.w*a.w
              + b.x*b.x + b.y*b.y + b.z*b.z + b.w*b.w;
    float sst = c.x*c.x + c.y*c.y + c.z*c.z + c.w*c.w
              + d.x*d.x + d.y*d.y + d.z*d.z + d.w*d.w;
    float sab = a.x*c.x + a.y*c.y + a.z*c.z + a.w*c.w
              + b.x*d.x + b.y*d.y + b.z*d.z + b.w*d.w;
    #pragma unroll
    for (int m = 1; m < 64; m <<= 1) {
        ssa += __shfl_xor(ssa, m, 64);
        sst += __shfl_xor(sst, m, 64);
        sab += __shfl_xor(sab, m, 64);
    }
    float sca = 1.0f / fmaxf(sqrtf(ssa), 1e-12f);
    float sct = 1.0f / fmaxf(sqrtf(sst), 1e-12f);
    uint4 oi, ot;
    oi.x = (unsigned)f2bf(a.x*sca) | ((unsigned)f2bf(a.y*sca) << 16);
    oi.y = (unsigned)f2bf(a.z*sca) | ((unsigned)f2bf(a.w*sca) << 16);
    oi.z = (unsigned)f2bf(b.x*sca) | ((unsigned)f2bf(b.y*sca) << 16);
    oi.w = (unsigned)f2bf(b.z*sca) | ((unsigned)f2bf(b.w*sca) << 16);
    ot.x = (unsigned)f2bf(c.x*sct) | ((unsigned)f2bf(c.y*sct) << 16);
    ot.y = (unsigned)f2bf(c.z*sct) | ((unsigned)f2bf(c.w*sct) << 16);
    ot.z = (unsigned)f2bf(d.x*sct) | ((unsigned)f2bf(d.y*sct) << 16);
    ot.w = (unsigned)f2bf(d.z*sct) | ((unsigned)f2bf(d.w*sct) << 16);
    *((uint4*)(imgn + (size_t)row * DIM) + lane) = oi;
    *((uint4*)(txtn + (size_t)row * DIM) + lane) = ot;
    if (lane == 0)
        sd[row] = (labels[row] < 0) ? sab * sca * sct : 0.0f;
}

// ---------------------------------------------------------------- fused GEMM
// Blocks [0, GEMM_BLKS): 128x128 tiles over a 512-col chunk (round-7 proven
//   schedule: 4 LDS buffers, depth-2 prefetch, counted vmcnt(4), 2 blk/CU).
// Blocks [GEMM_BLKS, +2048): class-sum path (8 slices x 128 cls x 2 mats).
// NEW: LDS bank-conflict swizzle (both-sides XOR involution, rule #21):
//   stage SOURCE k-chunk = (l&3) ^ ((l>>3)&3)  (LDS dest stays linear),
//   read slot            = q ^ ((lm>>1)&3).
//   Each 8-lane issue group then covers all 8 bank positions (2 parities x
//   4 slots) -> ds_read_b128 at the structural floor instead of ~3x.
#define ASYNC16(gp, lp) \
  __builtin_amdgcn_global_load_lds((const __attribute__((address_space(1))) void*)(gp), \
                                   (__attribute__((address_space(3))) void*)(lp), 16, 0, 0)

#define SFENCE __builtin_amdgcn_sched_barrier(0)

#define STAGE(b, tcol, k0)                                                    \
  {                                                                           \
    const unsigned short* Ap = A + (size_t)(rowBase + w*16 + srow) * DIM      \
                                 + (k0) + spsw;                               \
    const unsigned short* Bp = B + (size_t)((tcol) + w*16 + srow) * DIM       \
                                 + (k0) + spsw;                               \
    ASYNC16(Ap,            &Ald[b][(w*16) * 32]);                             \
    ASYNC16(Ap + 64 * DIM, &Ald[b][(64 + w*16) * 32]);                        \
    ASYNC16(Bp,            &Bld[b][(w*16) * 32]);                             \
    ASYNC16(Bp + 64 * DIM, &Bld[b][(64 + w*16) * 32]);                        \
  }

__global__ __launch_bounds__(256, 2) void gemm_fused_kernel(
    const unsigned short* __restrict__ imgn, const unsigned short* __restrict__ txtn,
    const int* __restrict__ labels,
    float* __restrict__ rs, float* __restrict__ cs,
    float* __restrict__ c_txt, float* __restrict__ c_img, int* __restrict__ cnt)
{
    __shared__ unsigned short Ald[4][BM * 32];
    __shared__ unsigned short Bld[4][BN * 32];
    __shared__ float red[2][BM];
    __shared__ float colb[2][CHUNK];
    __shared__ int   list[1024];
    __shared__ int   lcount;

    int tid  = threadIdx.x;

    // ---------------- class-sum path ----------------
    if (blockIdx.x >= GEMM_BLKS) {
        int blk = blockIdx.x - GEMM_BLKS;
        int cls = blk & (NCLS - 1);
        int mat = (blk >> 7) & 1;              // 0: txt sums, 1: img sums
        int slc = blk >> 8;                    // 0..7
        const unsigned* src = (const unsigned*)(mat ? imgn : txtn);
        float* dst = mat ? c_img : c_txt;
        if (tid == 0) lcount = 0;
        __syncthreads();
        int base0 = slc * 1024;
        #pragma unroll
        for (int it = 0; it < 4; ++it) {
            int i  = base0 + it * 256 + tid;
            int lb = labels[i];
            if (lb == cls) { int s = atomicAdd(&lcount, 1); list[s & 1023] = i; }
        }
        __syncthreads();
        int m = lcount;
        if (m == 0) return;
        if (mat == 0 && tid == 0) atomicAdd(&cnt[cls], m);
        float a0 = 0.f, a1 = 0.f;
        int r = 0;
        for (; r + 4 <= m; r += 4) {           // 4 independent loads in flight
            unsigned u0 = src[(size_t)list[r]   * (DIM/2) + tid];
            unsigned u1 = src[(size_t)list[r+1] * (DIM/2) + tid];
            unsigned u2 = src[(size_t)list[r+2] * (DIM/2) + tid];
            unsigned u3 = src[(size_t)list[r+3] * (DIM/2) + tid];
            a0 += __uint_as_float((u0 & 0xffffu) << 16) + __uint_as_float((u1 & 0xffffu) << 16)
                + __uint_as_float((u2 & 0xffffu) << 16) + __uint_as_float((u3 & 0xffffu) << 16);
            a1 += __uint_as_float(u0 & 0xffff0000u) + __uint_as_float(u1 & 0xffff0000u)
                + __uint_as_float(u2 & 0xffff0000u) + __uint_as_float(u3 & 0xffff0000u);
        }
        for (; r < m; ++r) {
            unsigned u = src[(size_t)list[r] * (DIM/2) + tid];
            a0 += __uint_as_float((u & 0xffffu) << 16);
            a1 += __uint_as_float(u & 0xffff0000u);
        }
        unsafeAtomicAdd(&dst[(size_t)cls * DIM + tid*2],     a0);
        unsafeAtomicAdd(&dst[(size_t)cls * DIM + tid*2 + 1], a1);
        return;
    }

    // ---------------- GEMM path ----------------
    int bid    = blockIdx.x;
    int rowblk = bid & 63;
    int chunk  = bid >> 6;        // consecutive bids share a chunk -> B L2-hot
    const unsigned short* A = imgn;
    const unsigned short* B = txtn;
    int rowBase  = rowblk * BM;
    int colBase0 = chunk * CHUNK;

    int lane = tid & 63;
    int w    = tid >> 6;
    int wr   = w >> 1, wc = w & 1;
    int q    = lane >> 4;
    int lm   = lane & 15;
    int qa   = q ^ ((lm >> 1) & 3);   // swizzled read slot

    float s_acc[16];
    #pragma unroll
    for (int i = 0; i < 16; ++i) s_acc[i] = 0.f;

    int srow = lane >> 2;                               // staging row in group
    int spsw = (((lane & 3) ^ ((lane >> 3) & 3)) * 8);  // swizzled src k-chunk

    const float C1 = SCALE * LOG2E;
    const float C2 = -MAXLOGIT * LOG2E;

    // prologue: stage step 0 -> buf0, step 1 -> buf1; wait only for step 0.
    STAGE(0, colBase0, 0);
    STAGE(1, colBase0, 32);
    SFENCE;
    asm volatile("s_waitcnt vmcnt(4)" ::: "memory");
    SFENCE;
    __builtin_amdgcn_s_barrier();
    SFENCE;

    #pragma unroll 1
    for (int tile = 0; tile < CHUNK / BN; ++tile) {
        f32x4 acc[4][4];
        #pragma unroll
        for (int mi = 0; mi < 4; ++mi)
          #pragma unroll
          for (int ni = 0; ni < 4; ++ni)
            acc[mi][ni] = (f32x4){0.f, 0.f, 0.f, 0.f};

        #pragma unroll
        for (int kt = 0; kt < DIM / 32; ++kt) {
            // step g = tile*16 + kt; tile*16 % 4 == 0 -> static buffer idx.
            const int bcur = kt & 3;
            const int bpf  = (kt + 2) & 3;
            int g2 = tile * 16 + kt + 2;
            if (g2 < 64) {
                int t2 = g2 >> 4, k2 = g2 & 15;
                STAGE(bpf, colBase0 + t2 * BN, k2 * 32);
            }

            short8 af[4], bf[4];
            #pragma unroll
            for (int mi = 0; mi < 4; ++mi)
                af[mi] = *(const short8*)(&Ald[bcur][(wr*64 + mi*16 + lm)*32 + qa*8]);
            #pragma unroll
            for (int ni = 0; ni < 4; ++ni)
                bf[ni] = *(const short8*)(&Bld[bcur][(wc*64 + ni*16 + lm)*32 + qa*8]);
            #pragma unroll
            for (int mi = 0; mi < 4; ++mi)
              #pragma unroll
              for (int ni = 0; ni < 4; ++ni)
                acc[mi][ni] = __builtin_amdgcn_mfma_f32_16x16x32_bf16(
                                  af[mi], bf[ni], acc[mi][ni], 0, 0, 0);

            // tile epilogue before the step wait: extra cover for prefetch.
            if (kt == DIM / 32 - 1) {
                #pragma unroll
                for (int ni = 0; ni < 4; ++ni) {
                    float csum = 0.f;
                    #pragma unroll
                    for (int mi = 0; mi < 4; ++mi) {
                      #pragma unroll
                      for (int r = 0; r < 4; ++r) {
                        float e = __builtin_amdgcn_exp2f(fmaf(acc[mi][ni][r], C1, C2));
                        s_acc[mi*4 + r] += e;
                        csum += e;
                      }
                    }
                    csum += __shfl_xor(csum, 16, 64);
                    csum += __shfl_xor(csum, 32, 64);
                    if (q == 0)
                        colb[wr][tile*BN + wc*64 + ni*16 + lm] = csum;
                }
            }

            // counted wait: <=4 outstanding => stage(g+1) landed; barrier =>
            // all waves' stage(g+1) landed before step g+1. Tail drains.
            SFENCE;
            if (g2 < 64) asm volatile("s_waitcnt vmcnt(4)" ::: "memory");
            else         asm volatile("s_waitcnt vmcnt(0)" ::: "memory");
            SFENCE;
            __builtin_amdgcn_s_barrier();
            SFENCE;
        }
    }

    // row stats: reduce across the 16 column-lanes (low 4 lane bits)
    #pragma unroll
    for (int idx = 0; idx < 16; ++idx) {
        float s = s_acc[idx];
        #pragma unroll
        for (int m = 1; m < 16; m <<= 1) s += __shfl_xor(s, m, 64);
        s_acc[idx] = s;
    }
    if (lm == 0) {
        #pragma unroll
        for (int idx = 0; idx < 16; ++idx) {
            int rl = wr*64 + (idx>>2)*16 + q*4 + (idx&3);
            red[wc][rl] = s_acc[idx];
        }
    }
    __syncthreads();
    if (tid < BM)
        unsafeAtomicAdd(&rs[rowBase + tid], red[0][tid] + red[1][tid]);
    for (int c = tid; c < CHUNK; c += 256)
        unsafeAtomicAdd(&cs[colBase0 + c], colb[0][c] + colb[1][c]);
}

// ---------------------------------------------------------------- final loss
// loss*2N = Sum_i (M + log rs_i) + Sum_i (M + log cs_i)
//           - 2*scale*[ Sum_l <c_img[l],c_txt[l]>/cnt_l + Sum_{lab=-1} <a_i,b_i> ]
__global__ __launch_bounds__(256) void loss_tail_kernel(
    const float* __restrict__ rs, const float* __restrict__ cs,
    const float* __restrict__ sd, const float* __restrict__ c_txt,
    const float* __restrict__ c_img, const int* __restrict__ cnt,
    float* __restrict__ out)
{
    __shared__ float wsum[4];
    int tid = threadIdx.x, lane = tid & 63, w = tid >> 6;
    int gidx = blockIdx.x * 256 + tid;           // 0..16383
    float local;
    if (gidx < N_ROWS)
        local = (MAXLOGIT + logf(rs[gidx])) - 2.0f * SCALE * sd[gidx];
    else
        local = MAXLOGIT + logf(cs[gidx - N_ROWS]);

    // class-dot portion: 2 classes per block, 4 dims per thread
    int cls = blockIdx.x * 2 + (tid >> 7);       // 0..127
    int e0  = (tid & 127) * 4;
    int n   = cnt[cls];
    if (n > 0) {
        float4 x = *(const float4*)(c_txt + (size_t)cls * DIM + e0);
        float4 y = *(const float4*)(c_img + (size_t)cls * DIM + e0);
        float dotp = x.x*y.x + x.y*y.y + x.z*y.z + x.w*y.w;
        local -= 2.0f * SCALE * dotp / (float)n;
    }

    #pragma unroll
    for (int m = 1; m < 64; m <<= 1) local += __shfl_xor(local, m, 64);
    if (lane == 0) wsum[w] = local;
    __syncthreads();
    if (tid == 0)
        unsafeAtomicAdd(out, (wsum[0] + wsum[1] + wsum[2] + wsum[3])
                             * (1.0f / (2 * N_ROWS)));
}

// ---------------------------------------------------------------- launch
extern "C" void kernel_launch(void* const* d_in, const int* in_sizes, int n_in,
                              void* d_out, int out_size, void* d_ws, size_t ws_size,
                              hipStream_t stream)
{
    const float* text   = (const float*)d_in[0];
    const float* image  = (const float*)d_in[1];
    const int*   labels = (const int*)d_in[2];

    unsigned short* imgn = (unsigned short*)d_ws;
    unsigned short* txtn = imgn + (size_t)N_ROWS * DIM;
    char* p = (char*)d_ws + 2 * (size_t)N_ROWS * DIM * sizeof(unsigned short);
    float* rs    = (float*)p;                       // 8192 f32  (zeroed)
    float* cs    = rs + N_ROWS;                     // 8192 f32  (zeroed)
    float* c_txt = cs + N_ROWS;                     // 128*512 f32 (zeroed)
    float* c_img = c_txt + (size_t)NCLS * DIM;      // 128*512 f32 (zeroed)
    int*   cnt   = (int*)(c_img + (size_t)NCLS * DIM); // 128 (zeroed)
    float* sd    = (float*)(cnt + NCLS);            // 8192 f32 (fully written)
    float* out = (float*)d_out;

    hipLaunchKernelGGL(norm_cast_kernel, dim3(N_ROWS / 4), dim3(256), 0, stream,
                       text, image, labels, imgn, txtn, (float4*)rs, sd, out);
    hipLaunchKernelGGL(gemm_fused_kernel, dim3(GEMM_BLKS + 2048), dim3(256), 0, stream,
                       imgn, txtn, labels, rs, cs, c_txt, c_img, cnt);
    hipLaunchKernelGGL(loss_tail_kernel, dim3(64), dim3(256), 0, stream,
                       rs, cs, sd, c_txt, c_img, cnt, out);
}